// Round 2
// baseline (313.627 us; speedup 1.0000x reference)
//
#include <hip/hip_runtime.h>

typedef float v2f __attribute__((ext_vector_type(2)));

#define Bb 256
#define Tt 512
#define Ll 128

// Barrier that waits only on LDS ops (lgkmcnt), NOT in-flight global loads:
// keeps the 2-step-ahead emit/y_true prefetch alive across the barrier.
__device__ __forceinline__ void bar_lgkm() {
  asm volatile("s_waitcnt lgkmcnt(0)" ::: "memory");
  __builtin_amdgcn_s_barrier();
  asm volatile("" ::: "memory");
}

__global__ __launch_bounds__(128) void crf_fused(
    const float* __restrict__ yt_g,   // y_true  (B,T,L) one-hot f32
    const float* __restrict__ yp_g,   // y_pred  (B,T,L) f32
    const float* __restrict__ tr_g,   // trans   (L,L)   f32
    float* __restrict__ out)          // (B,1)
{
  __shared__ __align__(16) float u_s[2][Ll];   // exp-domain alpha, double-buffered
  __shared__ int   lab_s[Tt];
  __shared__ float red_s[2][3];

  const int b   = blockIdx.x;
  const int tid = threadIdx.x;      // 0..127
  const int j   = tid;              // state owned by this lane (1 j per lane)

  const float* yp_b = yp_g + (size_t)b * Tt * Ll + j;
  const float* yt_b = yt_g + (size_t)b * Tt * Ll + j;

  // ---- E in registers: E2[k] = (exp(trans[2k][j]), exp(trans[2k+1][j])) ----
  v2f E2[64];
  #pragma unroll
  for (int k = 0; k < 64; ++k) {
    float a = tr_g[(2 * k) * Ll + j];
    float c = tr_g[(2 * k + 1) * Ll + j];
    v2f e; e.x = __expf(a); e.y = __expf(c);
    E2[k] = e;
  }

  // ---- t = 0 init: v0 = exp(emit0) (unnormalized), invariants:
  //   v_t[j] = exp(alpha_t[j] - alpha_{t-1}[0]);  C = sum log(v_{t-1}[0]) over steps
  float e0 = yp_b[0];
  float y0 = yt_b[0];
  float un = __expf(e0);
  float pt_acc = e0 * y0;
  u_s[0][j] = un;
  if (y0 > 0.5f) lab_s[0] = j;

  // prefetch emit/y_true for steps 1 and 2 (2-step lookahead)
  float pe0 = yp_b[(size_t)1 * Ll], py0 = yt_b[(size_t)1 * Ll];
  float pe1 = yp_b[(size_t)2 * Ll], py1 = yt_b[(size_t)2 * Ll];

  bar_lgkm();

  float C = 0.f;

  // ---- main recursion: steps 1..511, unrolled x2 (prefetch slots) ----
  for (int t = 1; t < Tt; t += 2) {
    // ================= step t (uses pe0/py0) =================
    {
      const float* usrc = u_s[(t + 1) & 1];         // v_{t-1}
      float p = usrc[0];                            // pivot (LDS broadcast)
      const float4* ub4 = (const float4*)usrc;
      v2f acc0 = {0.f, 0.f}, acc1 = {0.f, 0.f}, acc2 = {0.f, 0.f}, acc3 = {0.f, 0.f};
      #pragma unroll
      for (int k4 = 0; k4 < 32; k4 += 2) {
        float4 qa = ub4[k4];
        float4 qb = ub4[k4 + 1];
        v2f qa0; qa0.x = qa.x; qa0.y = qa.y;
        v2f qa1; qa1.x = qa.z; qa1.y = qa.w;
        v2f qb0; qb0.x = qb.x; qb0.y = qb.y;
        v2f qb1; qb1.x = qb.z; qb1.y = qb.w;
        acc0 += qa0 * E2[2 * k4 + 0];
        acc1 += qa1 * E2[2 * k4 + 1];
        acc2 += qb0 * E2[2 * k4 + 2];
        acc3 += qb1 * E2[2 * k4 + 3];
      }
      v2f aa = (acc0 + acc1) + (acc2 + acc3);
      float s = aa.x + aa.y;
      float w = __expf(pe0) * __builtin_amdgcn_rcpf(p);
      un = s * w;
      u_s[t & 1][j] = un;
      C += __logf(p);
      pt_acc += pe0 * py0;
      if (py0 > 0.5f) lab_s[t] = j;
      // reload slot 0 for step t+2
      int tn = (t + 2 < Tt) ? (t + 2) : (Tt - 1);
      pe0 = yp_b[(size_t)tn * Ll];
      py0 = yt_b[(size_t)tn * Ll];
      bar_lgkm();
    }
    // ================= step t+1 (uses pe1/py1) =================
    {
      const int tt = t + 1;
      const float* usrc = u_s[(tt + 1) & 1];        // v_t
      float p = usrc[0];
      const float4* ub4 = (const float4*)usrc;
      v2f acc0 = {0.f, 0.f}, acc1 = {0.f, 0.f}, acc2 = {0.f, 0.f}, acc3 = {0.f, 0.f};
      #pragma unroll
      for (int k4 = 0; k4 < 32; k4 += 2) {
        float4 qa = ub4[k4];
        float4 qb = ub4[k4 + 1];
        v2f qa0; qa0.x = qa.x; qa0.y = qa.y;
        v2f qa1; qa1.x = qa.z; qa1.y = qa.w;
        v2f qb0; qb0.x = qb.x; qb0.y = qb.y;
        v2f qb1; qb1.x = qb.z; qb1.y = qb.w;
        acc0 += qa0 * E2[2 * k4 + 0];
        acc1 += qa1 * E2[2 * k4 + 1];
        acc2 += qb0 * E2[2 * k4 + 2];
        acc3 += qb1 * E2[2 * k4 + 3];
      }
      v2f aa = (acc0 + acc1) + (acc2 + acc3);
      float s = aa.x + aa.y;
      float w = __expf(pe1) * __builtin_amdgcn_rcpf(p);
      un = s * w;
      u_s[tt & 1][j] = un;
      C += __logf(p);
      pt_acc += pe1 * py1;
      if (py1 > 0.5f) lab_s[tt] = j;
      // reload slot 1 for step t+3
      int tn = (t + 3 < Tt) ? (t + 3) : (Tt - 1);
      pe1 = yp_b[(size_t)tn * Ll];
      py1 = yt_b[(size_t)tn * Ll];
      bar_lgkm();
    }
  }

  // ---- trans score from labels (lab_s fully written; barrier above) ----
  float tr_acc = 0.f;
  for (int tt = tid; tt < Tt - 1; tt += 128)
    tr_acc += tr_g[lab_s[tt] * Ll + lab_s[tt + 1]];

  // ---- reductions: usum = sum_j v_T[j]; point; trans ----
  float usum = un, psum = pt_acc, tsum = tr_acc;
  #pragma unroll
  for (int off = 32; off; off >>= 1) {
    usum += __shfl_xor(usum, off);
    psum += __shfl_xor(psum, off);
    tsum += __shfl_xor(tsum, off);
  }
  if ((tid & 63) == 0) {
    int w = tid >> 6;
    red_s[w][0] = usum; red_s[w][1] = psum; red_s[w][2] = tsum;
  }
  bar_lgkm();
  if (tid == 0) {
    float ut = red_s[0][0] + red_s[1][0];
    float pt = red_s[0][1] + red_s[1][1];
    float tt2 = red_s[0][2] + red_s[1][2];
    // log_norm = C + log(sum_j v_T[j]);  out = log_norm - point - trans
    out[b] = C + __logf(ut) - pt - tt2;
  }
}

extern "C" void kernel_launch(void* const* d_in, const int* in_sizes, int n_in,
                              void* d_out, int out_size, void* d_ws, size_t ws_size,
                              hipStream_t stream) {
  const float* y_true = (const float*)d_in[0];
  const float* y_pred = (const float*)d_in[1];
  const float* trans  = (const float*)d_in[2];
  float* out = (float*)d_out;
  crf_fused<<<dim3(Bb), dim3(128), 0, stream>>>(y_true, y_pred, trans, out);
}

// Round 3
// 273.735 us; speedup vs baseline: 1.1457x; 1.1457x over previous
//
#include <hip/hip_runtime.h>

typedef float v2f __attribute__((ext_vector_type(2)));

#define Bb 256
#define Tt 512
#define Ll 128

// Barrier that waits only on LDS ops (lgkmcnt), NOT in-flight global loads:
// keeps the 2-step-ahead emit/y_true prefetch alive across the barrier.
__device__ __forceinline__ void bar_lgkm() {
  asm volatile("s_waitcnt lgkmcnt(0)" ::: "memory");
  __builtin_amdgcn_s_barrier();
  asm volatile("" ::: "memory");
}

// Layout: 128 threads = 2 waves. Lane (w,l): jp = w*32 + (l&31) in [0,64),
// owns states j = {2jp, 2jp+1} (v2f packed); ih = l>>5 selects i-half
// [64*ih, 64*ih+64). E slice lives in 128 VGPRs: E2[k] = exp(trans[64*ih+k][2jp..2jp+1]).
// Per step: 16x ds_read_b128 of the u half (broadcast), 32 pk_fma, one
// shfl_xor(32) to combine i-halves (in-wave), ds_write_b64 by ih==0 lanes,
// one lgkm-barrier. Deferred normalization by pivot p = u_prev[0].
__global__ __launch_bounds__(128, 1) void crf_fused(
    const float* __restrict__ yt_g,   // y_true  (B,T,L) one-hot f32
    const float* __restrict__ yp_g,   // y_pred  (B,T,L) f32
    const float* __restrict__ tr_g,   // trans   (L,L)   f32
    float* __restrict__ out)          // (B,1)
{
  __shared__ __align__(16) float u_s[2][Ll];   // exp-domain alpha, double-buffered
  __shared__ int   lab_s[Tt];
  __shared__ float red_s[2][3];

  const int b   = blockIdx.x;
  const int tid = threadIdx.x;        // 0..127
  const int w   = tid >> 6;
  const int l   = tid & 63;
  const int jp  = (w << 5) | (l & 31);  // state-pair 0..63
  const int ih  = l >> 5;               // i-half
  const int j0  = jp << 1;

  const float* yp_b = yp_g + (size_t)b * Tt * Ll + j0;
  const float* yt_b = yt_g + (size_t)b * Tt * Ll + j0;

  // ---- E slice in registers ----
  v2f E2[64];
  {
    const float* trp = tr_g + j0 + (size_t)(ih * 64) * Ll;
    #pragma unroll
    for (int k = 0; k < 64; ++k) {
      float2 tv = *(const float2*)(trp + (size_t)k * Ll);
      v2f e; e.x = __expf(tv.x); e.y = __expf(tv.y);
      E2[k] = e;
    }
  }

  // ---- t = 0 init ----
  float pt_acc = 0.f;
  v2f un;
  {
    float2 e0 = *(const float2*)(yp_b);
    float2 y0 = *(const float2*)(yt_b);
    un.x = __expf(e0.x); un.y = __expf(e0.y);
    if (ih == 0) {
      ((v2f*)u_s[0])[jp] = un;
      pt_acc = e0.x * y0.x + e0.y * y0.y;
      if (y0.x > 0.5f) lab_s[0] = j0;
      if (y0.y > 0.5f) lab_s[0] = j0 + 1;
    }
  }
  // 2-step-lookahead emit/y_true prefetch
  float2 pe0 = *(const float2*)(yp_b + (size_t)1 * Ll);
  float2 py0 = *(const float2*)(yt_b + (size_t)1 * Ll);
  float2 pe1 = *(const float2*)(yp_b + (size_t)2 * Ll);
  float2 py1 = *(const float2*)(yt_b + (size_t)2 * Ll);
  bar_lgkm();

  float C = 0.f;

#define CRF_STEP(T_, PE_, PY_, TN_)                                          \
  {                                                                          \
    const float* usrc = u_s[((T_) + 1) & 1];                                 \
    float p = usrc[0];                                                       \
    const float4* ub4 = (const float4*)(usrc + (ih << 6));                   \
    v2f a0 = {0.f, 0.f}, a1 = {0.f, 0.f}, a2 = {0.f, 0.f}, a3 = {0.f, 0.f};  \
    _Pragma("unroll")                                                        \
    for (int kk = 0; kk < 16; ++kk) {                                        \
      float4 q = ub4[kk];                                                    \
      a0 += E2[4 * kk + 0] * q.x;                                            \
      a1 += E2[4 * kk + 1] * q.y;                                            \
      a2 += E2[4 * kk + 2] * q.z;                                            \
      a3 += E2[4 * kk + 3] * q.w;                                            \
    }                                                                        \
    v2f aa = (a0 + a1) + (a2 + a3);                                          \
    aa.x += __shfl_xor(aa.x, 32);                                            \
    aa.y += __shfl_xor(aa.y, 32);                                            \
    float rinv = __builtin_amdgcn_rcpf(p);                                   \
    un.x = aa.x * (__expf(PE_.x) * rinv);                                    \
    un.y = aa.y * (__expf(PE_.y) * rinv);                                    \
    if (ih == 0) {                                                           \
      ((v2f*)u_s[(T_) & 1])[jp] = un;                                        \
      pt_acc += PE_.x * PY_.x + PE_.y * PY_.y;                               \
      if (PY_.x > 0.5f) lab_s[(T_)] = j0;                                    \
      if (PY_.y > 0.5f) lab_s[(T_)] = j0 + 1;                                \
    }                                                                        \
    C += __logf(p);                                                          \
    {                                                                        \
      int tn = (TN_) < Tt ? (TN_) : (Tt - 1);                                \
      PE_ = *(const float2*)(yp_b + (size_t)tn * Ll);                        \
      PY_ = *(const float2*)(yt_b + (size_t)tn * Ll);                        \
    }                                                                        \
    bar_lgkm();                                                              \
  }

  // steps 1..510 as 255 unrolled pairs, then explicit tail step 511
  for (int t = 1; t <= Tt - 3; t += 2) {
    CRF_STEP(t,     pe0, py0, t + 2)
    CRF_STEP(t + 1, pe1, py1, t + 3)
  }
  CRF_STEP(Tt - 1, pe0, py0, Tt - 1)

  // ---- trans score from labels ----
  float tr_acc = 0.f;
  #pragma unroll
  for (int tt = tid; tt < Tt - 1; tt += 128)
    tr_acc += tr_g[lab_s[tt] * Ll + lab_s[tt + 1]];

  // ---- reductions ----
  float usum = un.x + un.y;   // duplicated across ih (factor 2 handled below)
  float psum = pt_acc;        // only ih==0 lanes contributed
  float tsum = tr_acc;
  #pragma unroll
  for (int off = 32; off; off >>= 1) {
    usum += __shfl_xor(usum, off);
    psum += __shfl_xor(psum, off);
    tsum += __shfl_xor(tsum, off);
  }
  if (l == 0) { red_s[w][0] = usum; red_s[w][1] = psum; red_s[w][2] = tsum; }
  bar_lgkm();
  if (tid == 0) {
    float ut  = (red_s[0][0] + red_s[1][0]) * 0.5f;
    float pt  = red_s[0][1] + red_s[1][1];
    float tt2 = red_s[0][2] + red_s[1][2];
    out[b] = C + __logf(ut) - pt - tt2;
  }
#undef CRF_STEP
}

extern "C" void kernel_launch(void* const* d_in, const int* in_sizes, int n_in,
                              void* d_out, int out_size, void* d_ws, size_t ws_size,
                              hipStream_t stream) {
  const float* y_true = (const float*)d_in[0];
  const float* y_pred = (const float*)d_in[1];
  const float* trans  = (const float*)d_in[2];
  float* out = (float*)d_out;
  crf_fused<<<dim3(Bb), dim3(128), 0, stream>>>(y_true, y_pred, trans, out);
}

// Round 4
// 207.538 us; speedup vs baseline: 1.5112x; 1.3190x over previous
//
#include <hip/hip_runtime.h>

typedef float f32x8 __attribute__((ext_vector_type(8)));

#define Bb 256
#define Tt 512
#define Ll 128

// Barrier that waits only on LDS ops (lgkmcnt), NOT in-flight global loads:
// keeps the 2-step-ahead emit/y_true prefetch alive across the barrier.
__device__ __forceinline__ void bar_lgkm() {
  asm volatile("s_waitcnt lgkmcnt(0)" ::: "memory");
  __builtin_amdgcn_s_barrier();
  asm volatile("" ::: "memory");
}

// 256 threads = 4 waves. Lane (w,l): j = 32w + (l&31) (one state per lane,
// each j held by the ih=0 and ih=1 lanes of one wave); ih = l>>5 selects
// i-half [64*ih, 64*ih+64). E slice = 64 floats/lane in EIGHT NAMED f32x8
// ext-vector variables (SSA values -> cannot be demoted to scratch, unlike
// the alloca'd arrays of rounds 1-3 which all spilled and made every step
// L2-bound on reloads). Per step: broadcast LDS read of the u-half, 4
// independent f32x8 FMA chains, one in-wave shfl_xor(32) half-combine,
// single-writer ds_write, one lgkm-only barrier.
__global__ __launch_bounds__(256, 1) void crf_fused(
    const float* __restrict__ yt_g,   // y_true  (B,T,L) one-hot f32
    const float* __restrict__ yp_g,   // y_pred  (B,T,L) f32
    const float* __restrict__ tr_g,   // trans   (L,L)   f32
    float* __restrict__ out)          // (B,1)
{
  __shared__ __align__(32) float u_s[2][Ll];   // exp-domain alpha, double-buffered
  __shared__ int   lab_s[Tt];
  __shared__ float red_s[4][3];

  const int b   = blockIdx.x;
  const int tid = threadIdx.x;        // 0..255
  const int w   = tid >> 6;
  const int l   = tid & 63;
  const int j   = (w << 5) | (l & 31);   // state 0..127
  const int ih  = l >> 5;                // i-half

  const float* yp_b = yp_g + (size_t)b * Tt * Ll + j;
  const float* yt_b = yt_g + (size_t)b * Tt * Ll + j;

  // ---- E slice in registers: Ee{n}[k] = exp(trans[64*ih + 8n + k][j]) ----
  f32x8 Ee0, Ee1, Ee2, Ee3, Ee4, Ee5, Ee6, Ee7;
  {
    const float* trp = tr_g + (size_t)(ih << 6) * Ll + j;
#define LDE(V, B_)                                                      \
    V[0] = __expf(trp[(B_ + 0) * Ll]); V[1] = __expf(trp[(B_ + 1) * Ll]); \
    V[2] = __expf(trp[(B_ + 2) * Ll]); V[3] = __expf(trp[(B_ + 3) * Ll]); \
    V[4] = __expf(trp[(B_ + 4) * Ll]); V[5] = __expf(trp[(B_ + 5) * Ll]); \
    V[6] = __expf(trp[(B_ + 6) * Ll]); V[7] = __expf(trp[(B_ + 7) * Ll]);
    LDE(Ee0, 0)  LDE(Ee1, 8)  LDE(Ee2, 16) LDE(Ee3, 24)
    LDE(Ee4, 32) LDE(Ee5, 40) LDE(Ee6, 48) LDE(Ee7, 56)
#undef LDE
  }

  // ---- t = 0 init: v0 = exp(emit0); invariants:
  //   v_t[j] = exp(alpha_t[j] - alpha_{t-1}[0]);  C = sum over steps of log(v[0])
  float pt_acc = 0.f, C = 0.f, un = 0.f;
  {
    float e0 = yp_b[0], y0 = yt_b[0];
    un = __expf(e0);
    if (ih == 0) {
      u_s[0][j] = un;
      pt_acc = e0 * y0;
      if (y0 > 0.5f) lab_s[0] = j;
    }
  }
  // 2-step-lookahead emit/y_true prefetch
  float pe0 = yp_b[(size_t)1 * Ll], py0 = yt_b[(size_t)1 * Ll];
  float pe1 = yp_b[(size_t)2 * Ll], py1 = yt_b[(size_t)2 * Ll];
  bar_lgkm();

#define CRF_STEP(T_, PE_, PY_, TN_)                                        \
  {                                                                        \
    const float* usrc = u_s[((T_) + 1) & 1];                               \
    float p = usrc[0];                          /* pivot, issued first */  \
    const f32x8* uh = (const f32x8*)(usrc + (ih << 6));                    \
    f32x8 q0 = uh[0], q1 = uh[1], q2 = uh[2], q3 = uh[3];                  \
    f32x8 q4 = uh[4], q5 = uh[5], q6 = uh[6], q7 = uh[7];                  \
    float wc = __expf(PE_) * __builtin_amdgcn_rcpf(p); /* off u-chain */   \
    f32x8 a0 = q0 * Ee0; f32x8 a1 = q1 * Ee1;                              \
    f32x8 a2 = q2 * Ee2; f32x8 a3 = q3 * Ee3;                              \
    a0 += q4 * Ee4; a1 += q5 * Ee5; a2 += q6 * Ee6; a3 += q7 * Ee7;        \
    f32x8 aa = (a0 + a1) + (a2 + a3);                                      \
    float s = ((aa[0] + aa[1]) + (aa[2] + aa[3]))                          \
            + ((aa[4] + aa[5]) + (aa[6] + aa[7]));                         \
    s += __shfl_xor(s, 32);                    /* combine i-halves */      \
    un = s * wc;                                                           \
    if (ih == 0) {                                                         \
      u_s[(T_) & 1][j] = un;                                               \
      pt_acc += PE_ * PY_;                                                 \
      if (PY_ > 0.5f) lab_s[(T_)] = j;                                     \
    }                                                                      \
    C += __logf(p);                            /* off-chain */             \
    {                                                                      \
      int tn = (TN_) < Tt ? (TN_) : (Tt - 1);                              \
      PE_ = yp_b[(size_t)tn * Ll];                                         \
      PY_ = yt_b[(size_t)tn * Ll];                                         \
    }                                                                      \
    bar_lgkm();                                                            \
  }

  // steps 1..510 as unrolled pairs, then explicit tail step 511
  for (int t = 1; t <= Tt - 3; t += 2) {
    CRF_STEP(t,     pe0, py0, t + 2)
    CRF_STEP(t + 1, pe1, py1, t + 3)
  }
  CRF_STEP(Tt - 1, pe0, py0, Tt - 1)
#undef CRF_STEP

  // ---- trans score from labels ----
  float tr_acc = 0.f;
  for (int tt = tid; tt < Tt - 1; tt += 256)
    tr_acc += tr_g[lab_s[tt] * Ll + lab_s[tt + 1]];

  // ---- reductions: usum counts each j once (gate ih==0) ----
  float usum = (ih == 0) ? un : 0.f;
  float psum = pt_acc;
  float tsum = tr_acc;
  #pragma unroll
  for (int off = 32; off; off >>= 1) {
    usum += __shfl_xor(usum, off);
    psum += __shfl_xor(psum, off);
    tsum += __shfl_xor(tsum, off);
  }
  if (l == 0) { red_s[w][0] = usum; red_s[w][1] = psum; red_s[w][2] = tsum; }
  bar_lgkm();
  if (tid == 0) {
    float ut  = red_s[0][0] + red_s[1][0] + red_s[2][0] + red_s[3][0];
    float pt  = red_s[0][1] + red_s[1][1] + red_s[2][1] + red_s[3][1];
    float tt2 = red_s[0][2] + red_s[1][2] + red_s[2][2] + red_s[3][2];
    out[b] = C + __logf(ut) - pt - tt2;
  }
}

extern "C" void kernel_launch(void* const* d_in, const int* in_sizes, int n_in,
                              void* d_out, int out_size, void* d_ws, size_t ws_size,
                              hipStream_t stream) {
  const float* y_true = (const float*)d_in[0];
  const float* y_pred = (const float*)d_in[1];
  const float* trans  = (const float*)d_in[2];
  float* out = (float*)d_out;
  crf_fused<<<dim3(Bb), dim3(256), 0, stream>>>(y_true, y_pred, trans, out);
}

// Round 5
// 195.737 us; speedup vs baseline: 1.6023x; 1.0603x over previous
//
#include <hip/hip_runtime.h>

typedef float f32x8 __attribute__((ext_vector_type(8)));

#define Bb 256
#define Tt 512
#define Ll 128

// Barrier that waits only on LDS ops (lgkmcnt), NOT in-flight global loads:
// keeps the 2-step-ahead emit/y_true prefetch alive across the barrier.
__device__ __forceinline__ void bar_lgkm() {
  asm volatile("s_waitcnt lgkmcnt(0)" ::: "memory");
  __builtin_amdgcn_s_barrier();
  asm volatile("" ::: "memory");
}

// 512 threads = 8 waves. Lane (w,l): j = 16w + (l&15) (state 0..127, each j
// held by 4 lanes), iq = l>>4 selects i-quarter [32*iq, 32*iq+32).
// E slice = 32 floats/lane in FOUR named f32x8 SSA values (32 VGPRs) --
// small enough to stay register-resident even under the ~80-VGPR allocator
// cap that spilled E in rounds 1-4 (the entire ~1100 cyc/step wall was the
// 64KB/step L2-backed scratch reload of E). waves_per_eu pinned to 2 to
// remove the occupancy heuristic from the register budget.
// Per step: broadcast pivot + 4x ds_read_b128 of the u quarter, 16 FMA
// (4 f32x8 chains), shfl_xor(16)+shfl_xor(32) quarter-combine, single-writer
// ds_write, one lgkm-only barrier. Deferred normalization by pivot
// p = u_prev[0]; C accumulates log(p).
__global__ __attribute__((amdgpu_flat_work_group_size(512, 512),
                          amdgpu_waves_per_eu(2, 2)))
void crf_fused(
    const float* __restrict__ yt_g,   // y_true  (B,T,L) one-hot f32
    const float* __restrict__ yp_g,   // y_pred  (B,T,L) f32
    const float* __restrict__ tr_g,   // trans   (L,L)   f32
    float* __restrict__ out)          // (B,1)
{
  __shared__ __align__(32) float u_s[2][Ll];   // exp-domain alpha, double-buffered
  __shared__ int   lab_s[Tt];
  __shared__ float red_s[8][3];

  const int b   = blockIdx.x;
  const int tid = threadIdx.x;        // 0..511
  const int w   = tid >> 6;           // wave 0..7
  const int l   = tid & 63;
  const int j   = (w << 4) | (l & 15);   // state 0..127
  const int iq  = l >> 4;                // i-quarter 0..3

  const float* yp_b = yp_g + (size_t)b * Tt * Ll + j;
  const float* yt_b = yt_g + (size_t)b * Tt * Ll + j;

  // ---- E slice in registers: Eq{n}[k] = exp(trans[32*iq + 8n + k][j]) ----
  f32x8 Eq0, Eq1, Eq2, Eq3;
  {
    const float* trp = tr_g + (size_t)(iq << 5) * Ll + j;
#define LDE(V, B_)                                                        \
    V[0] = __expf(trp[(B_ + 0) * Ll]); V[1] = __expf(trp[(B_ + 1) * Ll]); \
    V[2] = __expf(trp[(B_ + 2) * Ll]); V[3] = __expf(trp[(B_ + 3) * Ll]); \
    V[4] = __expf(trp[(B_ + 4) * Ll]); V[5] = __expf(trp[(B_ + 5) * Ll]); \
    V[6] = __expf(trp[(B_ + 6) * Ll]); V[7] = __expf(trp[(B_ + 7) * Ll]);
    LDE(Eq0, 0) LDE(Eq1, 8) LDE(Eq2, 16) LDE(Eq3, 24)
#undef LDE
  }

  // ---- t = 0 init: v0 = exp(emit0); invariants:
  //   v_t[j] = exp(alpha_t[j] - alpha_{t-1}[0]);  C = sum over steps of log(v[0])
  float pt_acc = 0.f, C = 0.f, un = 0.f;
  {
    float e0 = yp_b[0], y0 = yt_b[0];
    un = __expf(e0);
    if (iq == 0) {
      u_s[0][j] = un;
      pt_acc = e0 * y0;
      if (y0 > 0.5f) lab_s[0] = j;
    }
  }
  // 2-step-lookahead emit/y_true prefetch
  float pe0 = yp_b[(size_t)1 * Ll], py0 = yt_b[(size_t)1 * Ll];
  float pe1 = yp_b[(size_t)2 * Ll], py1 = yt_b[(size_t)2 * Ll];
  bar_lgkm();

#define CRF_STEP(T_, PE_, PY_, TN_)                                        \
  {                                                                        \
    const float* usrc = u_s[((T_) + 1) & 1];                               \
    float p = usrc[0];                          /* pivot, issued first */  \
    const f32x8* uh = (const f32x8*)(usrc + (iq << 5));                    \
    f32x8 q0 = uh[0], q1 = uh[1], q2 = uh[2], q3 = uh[3];                  \
    float wc = __expf(PE_) * __builtin_amdgcn_rcpf(p); /* off u-chain */   \
    f32x8 a0 = q0 * Eq0;                                                   \
    f32x8 a1 = q1 * Eq1;                                                   \
    a0 += q2 * Eq2;                                                        \
    a1 += q3 * Eq3;                                                        \
    f32x8 aa = a0 + a1;                                                    \
    float s = ((aa[0] + aa[1]) + (aa[2] + aa[3]))                          \
            + ((aa[4] + aa[5]) + (aa[6] + aa[7]));                         \
    s += __shfl_xor(s, 16);                    /* combine i-quarters */    \
    s += __shfl_xor(s, 32);                                                \
    un = s * wc;                                                           \
    if (iq == 0) {                                                         \
      u_s[(T_) & 1][j] = un;                                               \
      pt_acc += PE_ * PY_;                                                 \
      if (PY_ > 0.5f) lab_s[(T_)] = j;                                     \
    }                                                                      \
    C += __logf(p);                            /* off-chain */             \
    {                                                                      \
      int tn = (TN_) < Tt ? (TN_) : (Tt - 1);                              \
      PE_ = yp_b[(size_t)tn * Ll];                                         \
      PY_ = yt_b[(size_t)tn * Ll];                                         \
    }                                                                      \
    bar_lgkm();                                                            \
  }

  // steps 1..510 as unrolled pairs, then explicit tail step 511
  for (int t = 1; t <= Tt - 3; t += 2) {
    CRF_STEP(t,     pe0, py0, t + 2)
    CRF_STEP(t + 1, pe1, py1, t + 3)
  }
  CRF_STEP(Tt - 1, pe0, py0, Tt - 1)
#undef CRF_STEP

  // ---- trans score from labels ----
  float tr_acc = 0.f;
  if (tid < Tt - 1)
    tr_acc = tr_g[lab_s[tid] * Ll + lab_s[tid + 1]];

  // ---- reductions: usum counts each j once (gate iq==0) ----
  float usum = (iq == 0) ? un : 0.f;
  float psum = pt_acc;     // only iq==0 lanes contributed
  float tsum = tr_acc;
  #pragma unroll
  for (int off = 32; off; off >>= 1) {
    usum += __shfl_xor(usum, off);
    psum += __shfl_xor(psum, off);
    tsum += __shfl_xor(tsum, off);
  }
  if (l == 0) { red_s[w][0] = usum; red_s[w][1] = psum; red_s[w][2] = tsum; }
  bar_lgkm();
  if (tid == 0) {
    float ut = 0.f, pt = 0.f, tt2 = 0.f;
    #pragma unroll
    for (int k = 0; k < 8; ++k) {
      ut  += red_s[k][0];
      pt  += red_s[k][1];
      tt2 += red_s[k][2];
    }
    out[b] = C + __logf(ut) - pt - tt2;
  }
}

extern "C" void kernel_launch(void* const* d_in, const int* in_sizes, int n_in,
                              void* d_out, int out_size, void* d_ws, size_t ws_size,
                              hipStream_t stream) {
  const float* y_true = (const float*)d_in[0];
  const float* y_pred = (const float*)d_in[1];
  const float* trans  = (const float*)d_in[2];
  float* out = (float*)d_out;
  crf_fused<<<dim3(Bb), dim3(512), 0, stream>>>(y_true, y_pred, trans, out);
}